// Round 5
// baseline (869.999 us; speedup 1.0000x reference)
//
#include <hip/hip_runtime.h>
#include <hip/hip_bf16.h>

#define N_NODES 4096
#define IN_DIM  256
#define OUT_DIM 128
#define EDGE_DIM 64
#define N_SAMPLE 128
#define GRID 1024
#define NTHR 256

__device__ __forceinline__ float wsum64(float v) {
#pragma unroll
  for (int off = 32; off; off >>= 1) v += __shfl_xor(v, off, 64);
  return v;
}
__device__ __forceinline__ float wmax64(float v) {
#pragma unroll
  for (int off = 32; off; off >>= 1) v = fmaxf(v, __shfl_xor(v, off, 64));
  return v;
}

// Poison-tolerant single-use grid barrier. Counter starts as 0xAAAAAAAA
// (harness poison) or GRID (leftover from a completed prior run); every
// block CASes both to 0 at kernel start BEFORE any of its own arrivals,
// so a live counter can never be clobbered.
__device__ __forceinline__ void gbar(unsigned int* cnt) {
  __threadfence();                 // release: prior writes visible device-wide
  __syncthreads();
  if (threadIdx.x == 0) {
    __hip_atomic_fetch_add(cnt, 1u, __ATOMIC_ACQ_REL, __HIP_MEMORY_SCOPE_AGENT);
    while (__hip_atomic_load(cnt, __ATOMIC_ACQUIRE, __HIP_MEMORY_SCOPE_AGENT) < GRID)
      __builtin_amdgcn_s_sleep(2);
  }
  __syncthreads();
  __threadfence();                 // acquire side
}

__global__ void __launch_bounds__(NTHR, 4)
mega_kernel(const float* __restrict__ feat, const int* __restrict__ eidx,
            const int* __restrict__ neigh, const int* __restrict__ tu,
            const float* __restrict__ emb, const float* __restrict__ W,
            const float* __restrict__ W2, const float* __restrict__ W3,
            const float* __restrict__ Bv, const float* __restrict__ a,
            float* __restrict__ x, float* __restrict__ s1, float* __restrict__ s2,
            float* __restrict__ s3, float* __restrict__ Y,
            float* __restrict__ out, float* __restrict__ emb_new,
            unsigned int* __restrict__ cnt, int n, int rows) {
  const int t   = threadIdx.x;
  const int bid = blockIdx.x;
  __shared__ __align__(16) unsigned char smem_raw[18432];
  float* smf = reinterpret_cast<float*>(smem_raw);

  // ---- barrier counter init (poison- and leftover-tolerant) ----
  if (t == 0) {
#pragma unroll
    for (int k = 0; k < 3; ++k) {
      unsigned int e0 = 0xAAAAAAAAu;
      __hip_atomic_compare_exchange_strong(&cnt[k], &e0, 0u, __ATOMIC_ACQ_REL,
                                           __ATOMIC_RELAXED, __HIP_MEMORY_SCOPE_AGENT);
      unsigned int e1 = (unsigned int)GRID;
      __hip_atomic_compare_exchange_strong(&cnt[k], &e1, 0u, __ATOMIC_ACQ_REL,
                                           __ATOMIC_RELAXED, __HIP_MEMORY_SCOPE_AGENT);
    }
  }

  // ================= Phase A: x = feat@W, s1, s2 (4 rows/block) ============
  {
    const int v0 = bid * 4;
    float* fA    = smf;            // [4][256]  @0      (4 KB)
    float* partA = smf + 1024;     // [2][4][128] @4KB  (4 KB)
    float* redA  = smf + 2048;     // [2][2][4] ×2 stats @8KB (128 B)
    *reinterpret_cast<float4*>(&fA[t * 4]) =
        *reinterpret_cast<const float4*>(&feat[v0 * IN_DIM + t * 4]);
    __syncthreads();
    const int h = t >> 7, c = t & 127;
    float ac0 = 0.f, ac1 = 0.f, ac2 = 0.f, ac3 = 0.f;
    const int kb = h * 128;
    for (int k = kb; k < kb + 128; k += 4) {
      const float w0 = W[(k + 0) * OUT_DIM + c];
      const float w1 = W[(k + 1) * OUT_DIM + c];
      const float w2 = W[(k + 2) * OUT_DIM + c];
      const float w3 = W[(k + 3) * OUT_DIM + c];
      const float4 f0 = *reinterpret_cast<const float4*>(&fA[0 * 256 + k]);
      const float4 f1 = *reinterpret_cast<const float4*>(&fA[1 * 256 + k]);
      const float4 f2 = *reinterpret_cast<const float4*>(&fA[2 * 256 + k]);
      const float4 f3 = *reinterpret_cast<const float4*>(&fA[3 * 256 + k]);
      ac0 += f0.x * w0 + f0.y * w1 + f0.z * w2 + f0.w * w3;
      ac1 += f1.x * w0 + f1.y * w1 + f1.z * w2 + f1.w * w3;
      ac2 += f2.x * w0 + f2.y * w1 + f2.z * w2 + f2.w * w3;
      ac3 += f3.x * w0 + f3.y * w1 + f3.z * w2 + f3.w * w3;
    }
    partA[(h * 4 + 0) * 128 + c] = ac0;
    partA[(h * 4 + 1) * 128 + c] = ac1;
    partA[(h * 4 + 2) * 128 + c] = ac2;
    partA[(h * 4 + 3) * 128 + c] = ac3;
    __syncthreads();
    if (t < 128) {
      const float a1 = a[t], a2v = a[OUT_DIM + t];
      float p1[4], p2[4];
#pragma unroll
      for (int r = 0; r < 4; ++r) {
        const float xv = partA[(0 * 4 + r) * 128 + t] + partA[(1 * 4 + r) * 128 + t];
        x[(v0 + r) * OUT_DIM + t] = xv;
        p1[r] = xv * a1;
        p2[r] = xv * a2v;
      }
      const int wv = t >> 6;
#pragma unroll
      for (int r = 0; r < 4; ++r) {
        const float q1 = wsum64(p1[r]);
        const float q2 = wsum64(p2[r]);
        if ((t & 63) == 0) { redA[wv * 4 + r] = q1; redA[8 + wv * 4 + r] = q2; }
      }
    }
    __syncthreads();
    if (t < 4) {
      s1[v0 + t] = redA[t] + redA[4 + t];
      s2[v0 + t] = redA[8 + t] + redA[12 + t];
    }
  }

  // ================= Phase B: s3[r] = emb[r] . a3 ==========================
  {
    const int wv = t >> 6, l = t & 63;
    const float a3l = a[2 * OUT_DIM + l];
    for (int r = bid * 4 + wv; r < rows; r += 4 * GRID) {
      float c3 = emb[r * EDGE_DIM + l] * a3l;
      c3 = wsum64(c3);
      if (l == 0) s3[r] = c3;
    }
  }

  gbar(&cnt[0]);

  // ================= Phase C: attention + aggregate + ELU ==================
  {
    float* attC = smf;                                   // [128] @0
    int*   usC  = reinterpret_cast<int*>(smf + 128);     // [128]
    float* redC = smf + 256;                             // [4]
    float4* hpC = reinterpret_cast<float4*>(smem_raw + 2048); // [8][32] (4 KB)
    const int w = t >> 6, l = t & 63;
    for (int v = bid; v < N_NODES; v += GRID) {
      if (t < N_SAMPLE) {
        const int u = neigh[v * N_SAMPLE + t];
        usC[t] = u;
        float e = s1[v] + s2[u] + s3[eidx[v * N_NODES + u]];
        e = e > 0.f ? e : 0.2f * e;                      // leaky_relu 0.2
        attC[t] = e;
        const float m = wmax64(e);
        if (l == 0) redC[w] = m;
      }
      __syncthreads();
      const float m = fmaxf(redC[0], redC[1]);
      if (t < N_SAMPLE) {
        const float p = __expf(attC[t] - m);
        attC[t] = p;
        const float s = wsum64(p);
        if (l == 0) redC[2 + w] = s;
      }
      __syncthreads();
      const float inv = 1.0f / (redC[2] + redC[3]);
      // aggregation: wave w owns samples w*32..w*32+31; 2 samples per instr
      const int half = l >> 5, cq = l & 31;
      float4 h4 = make_float4(0.f, 0.f, 0.f, 0.f);
      const int s0 = w * 32;
#pragma unroll
      for (int it = 0; it < 16; ++it) {
        const int s = s0 + 2 * it + half;
        const float av = attC[s];
        const float4 xv = *reinterpret_cast<const float4*>(&x[usC[s] * OUT_DIM + cq * 4]);
        h4.x += av * xv.x; h4.y += av * xv.y; h4.z += av * xv.z; h4.w += av * xv.w;
      }
      hpC[(w * 2 + half) * 32 + cq] = h4;
      __syncthreads();
      if (t < 32) {
        float4 H = make_float4(0.f, 0.f, 0.f, 0.f);
#pragma unroll
        for (int p = 0; p < 8; ++p) {
          const float4 v4 = hpC[p * 32 + t];
          H.x += v4.x; H.y += v4.y; H.z += v4.z; H.w += v4.w;
        }
        const float4 xs = *reinterpret_cast<const float4*>(&x[v * OUT_DIM + t * 4]);
        float o0 = H.x * inv + xs.x, o1 = H.y * inv + xs.y;
        float o2 = H.z * inv + xs.z, o3 = H.w * inv + xs.w;
        o0 = o0 > 0.f ? o0 : expm1f(o0);
        o1 = o1 > 0.f ? o1 : expm1f(o1);
        o2 = o2 > 0.f ? o2 : expm1f(o2);
        o3 = o3 > 0.f ? o3 : expm1f(o3);
        *reinterpret_cast<float4*>(&out[v * OUT_DIM + t * 4]) = make_float4(o0, o1, o2, o3);
      }
      __syncthreads();
    }
  }

  gbar(&cnt[1]);

  // ================= Phase D: Y = out @ W2  (4 rows/block) =================
  {
    const int v0 = bid * 4;
    float* oD    = smf;            // [4][128] @0   (2 KB)
    float* partD = smf + 512;      // [4][4][64] @2KB (4 KB)
    if (t < 128)
      *reinterpret_cast<float4*>(&oD[t * 4]) =
          *reinterpret_cast<const float4*>(&out[v0 * OUT_DIM + t * 4]);
    __syncthreads();
    const int hq = t >> 6, cD = t & 63;
    float ac0 = 0.f, ac1 = 0.f, ac2 = 0.f, ac3 = 0.f;
    for (int k = hq * 32; k < hq * 32 + 32; ++k) {
      const float wv2 = W2[k * EDGE_DIM + cD];
      ac0 += oD[0 * 128 + k] * wv2;
      ac1 += oD[1 * 128 + k] * wv2;
      ac2 += oD[2 * 128 + k] * wv2;
      ac3 += oD[3 * 128 + k] * wv2;
    }
    partD[(hq * 4 + 0) * 64 + cD] = ac0;
    partD[(hq * 4 + 1) * 64 + cD] = ac1;
    partD[(hq * 4 + 2) * 64 + cD] = ac2;
    partD[(hq * 4 + 3) * 64 + cD] = ac3;
    __syncthreads();
    {
      const int r = t >> 6, c2 = t & 63;
      const float y = partD[(0 * 4 + r) * 64 + c2] + partD[(1 * 4 + r) * 64 + c2] +
                      partD[(2 * 4 + r) * 64 + c2] + partD[(3 * 4 + r) * 64 + c2];
      Y[(v0 + r) * EDGE_DIM + c2] = y;
    }
  }

  gbar(&cnt[2]);

  // ================= Phase E: fused edge update ============================
  {
    const int k0 = bid * 64;
    if (k0 < n) {
      float* AinE = smf;                                    // [64][68] (17408 B)
      int*   tusE = reinterpret_cast<int*>(smf + 4352);     // [128]
      if (t < 128) {
        const int idx = 2 * k0 + t;
        tusE[t] = (idx < 2 * n) ? tu[idx] : 0;
      }
      {
        const int e = t >> 2, q = t & 3;
        const int ke = k0 + e;
        if (ke < n) {
          const int i = tu[2 * ke], j = tu[2 * ke + 1];
          const int id = eidx[i * N_NODES + j];
#pragma unroll
          for (int kk = 0; kk < 16; kk += 4) {
            const int k = q * 16 + kk;
            *reinterpret_cast<float4*>(&AinE[e * 68 + k]) =
                *reinterpret_cast<const float4*>(&emb[id * EDGE_DIM + k]);
          }
        }
      }
      __syncthreads();
      const int e0 = (t >> 4) * 4;
      const int c0 = (t & 15) * 4;
      const float4 b4 = *reinterpret_cast<const float4*>(&Bv[c0]);
      float4 acc[4];
#pragma unroll
      for (int m = 0; m < 4; ++m) acc[m] = b4;
#pragma unroll 4
      for (int k = 0; k < EDGE_DIM; k += 4) {
        float4 av4[4];
#pragma unroll
        for (int m = 0; m < 4; ++m)
          av4[m] = *reinterpret_cast<const float4*>(&AinE[(e0 + m) * 68 + k]);
#pragma unroll
        for (int kk = 0; kk < 4; ++kk) {
          const float4 wv = *reinterpret_cast<const float4*>(&W3[(k + kk) * EDGE_DIM + c0]);
#pragma unroll
          for (int m = 0; m < 4; ++m) {
            const float av = reinterpret_cast<const float*>(&av4[m])[kk];
            acc[m].x += av * wv.x; acc[m].y += av * wv.y;
            acc[m].z += av * wv.z; acc[m].w += av * wv.w;
          }
        }
      }
#pragma unroll
      for (int m = 0; m < 4; ++m) {
        const int ke = k0 + e0 + m;
        if (ke < n) {
          const int i = tusE[2 * (e0 + m)], j = tusE[2 * (e0 + m) + 1];
          const float4 yi = *reinterpret_cast<const float4*>(&Y[i * EDGE_DIM + c0]);
          const float4 yj = *reinterpret_cast<const float4*>(&Y[j * EDGE_DIM + c0]);
          const float4 ek = *reinterpret_cast<const float4*>(&emb[(ke + 1) * EDGE_DIM + c0]);
          float4 r;
          r.x = fmaxf((acc[m].x + yi.x + yj.x) * ek.x, 0.f);
          r.y = fmaxf((acc[m].y + yi.y + yj.y) * ek.y, 0.f);
          r.z = fmaxf((acc[m].z + yi.z + yj.z) * ek.z, 0.f);
          r.w = fmaxf((acc[m].w + yi.w + yj.w) * ek.w, 0.f);
          *reinterpret_cast<float4*>(&emb_new[(ke + 1) * EDGE_DIM + c0]) = r;
        }
      }
      if (bid == 0 && t < 16) {
        const int cc = t * 4;
        const float4 b0 = *reinterpret_cast<const float4*>(&Bv[cc]);
        const float4 e0v = *reinterpret_cast<const float4*>(&emb[cc]);
        float4 r;
        r.x = fmaxf(b0.x * e0v.x, 0.f);
        r.y = fmaxf(b0.y * e0v.y, 0.f);
        r.z = fmaxf(b0.z * e0v.z, 0.f);
        r.w = fmaxf(b0.w * e0v.w, 0.f);
        *reinterpret_cast<float4*>(&emb_new[cc]) = r;
      }
    }
  }
}

extern "C" void kernel_launch(void* const* d_in, const int* in_sizes, int n_in,
                              void* d_out, int out_size, void* d_ws, size_t ws_size,
                              hipStream_t stream) {
  const float* feat  = (const float*)d_in[0];
  const int*   eidx  = (const int*)d_in[1];
  const int*   neigh = (const int*)d_in[2];
  const int*   tu    = (const int*)d_in[3];
  const float* emb   = (const float*)d_in[4];
  const float* W     = (const float*)d_in[5];
  const float* W2    = (const float*)d_in[6];
  const float* W3    = (const float*)d_in[7];
  const float* Bv    = (const float*)d_in[8];
  const float* a     = (const float*)d_in[9];
  const int n    = in_sizes[3] / 2;           // edges to update
  const int rows = in_sizes[4] / EDGE_DIM;    // n + 1 emb rows

  float* x  = (float*)d_ws;                   // 524288
  float* s1 = x + N_NODES * OUT_DIM;          // 4096
  float* s2 = s1 + N_NODES;                   // 4096
  float* s3 = s2 + N_NODES;                   // rows (pad 65552)
  float* Y  = s3 + 65552;                     // 262144
  unsigned int* cnt = (unsigned int*)(Y + N_NODES * EDGE_DIM);

  float* out_nodes = (float*)d_out;
  float* emb_new   = out_nodes + N_NODES * OUT_DIM;

  hipLaunchKernelGGL(mega_kernel, dim3(GRID), dim3(NTHR), 0, stream,
                     feat, eidx, neigh, tu, emb, W, W2, W3, Bv, a,
                     x, s1, s2, s3, Y, out_nodes, emb_new, cnt, n, rows);
}

// Round 6
// 181.474 us; speedup vs baseline: 4.7941x; 4.7941x over previous
//
#include <hip/hip_runtime.h>
#include <hip/hip_bf16.h>

#define N_NODES 4096
#define IN_DIM  256
#define OUT_DIM 128
#define EDGE_DIM 64
#define N_SAMPLE 128

__device__ __forceinline__ float wsum64(float v) {
#pragma unroll
  for (int off = 32; off; off >>= 1) v += __shfl_xor(v, off, 64);
  return v;
}
__device__ __forceinline__ float wmax64(float v) {
#pragma unroll
  for (int off = 32; off; off >>= 1) v = fmaxf(v, __shfl_xor(v, off, 64));
  return v;
}
__device__ __forceinline__ float sum16(float v) {   // reduce within 16-lane groups
#pragma unroll
  for (int off = 1; off < 16; off <<= 1) v += __shfl_xor(v, off, 64);
  return v;
}

// ========== K1: x = feat@W (8 rows/block) + s1,s2 epilogue + s3 ==========
__global__ void __launch_bounds__(128) k1_gemm_s_kernel(const float* __restrict__ feat,
                                                        const float* __restrict__ W,
                                                        const float* __restrict__ emb,
                                                        const float* __restrict__ a,
                                                        float* __restrict__ x,
                                                        float* __restrict__ s1,
                                                        float* __restrict__ s2,
                                                        float* __restrict__ s3, int rows) {
  const int t  = threadIdx.x;            // 0..127, owns col t
  const int v0 = blockIdx.x * 8;
  __shared__ float f[8][IN_DIM];
  __shared__ float redA[16], redB[16];
  {
    float4* f4 = reinterpret_cast<float4*>(&f[0][0]);
    const float4* g4 = reinterpret_cast<const float4*>(&feat[v0 * IN_DIM]);
#pragma unroll
    for (int i = 0; i < 4; ++i) f4[t + 128 * i] = g4[t + 128 * i];
  }
  __syncthreads();
  float acc[8] = {0.f, 0.f, 0.f, 0.f, 0.f, 0.f, 0.f, 0.f};
#pragma unroll 2
  for (int i = 0; i < IN_DIM; i += 4) {
    const float w0 = W[(i + 0) * OUT_DIM + t];
    const float w1 = W[(i + 1) * OUT_DIM + t];
    const float w2 = W[(i + 2) * OUT_DIM + t];
    const float w3 = W[(i + 3) * OUT_DIM + t];
#pragma unroll
    for (int r = 0; r < 8; ++r) {
      const float4 fv = *reinterpret_cast<const float4*>(&f[r][i]);
      acc[r] += fv.x * w0 + fv.y * w1 + fv.z * w2 + fv.w * w3;
    }
  }
  // write x + per-row dots with a1,a2 (block owns complete rows)
  const int wv = t >> 6;
  const float a1t = a[t], a2t = a[OUT_DIM + t];
#pragma unroll
  for (int r = 0; r < 8; ++r) {
    x[(v0 + r) * OUT_DIM + t] = acc[r];
    const float q1 = wsum64(acc[r] * a1t);
    const float q2 = wsum64(acc[r] * a2t);
    if ((t & 63) == 0) { redA[wv * 8 + r] = q1; redB[wv * 8 + r] = q2; }
  }
  __syncthreads();
  if (t < 8) {
    s1[v0 + t] = redA[t] + redA[8 + t];
    s2[v0 + t] = redB[t] + redB[8 + t];
  }
  // ---- s3: grid-strided, 4 emb rows per wave-iteration ----
  const int gw  = blockIdx.x * 2 + wv;   // global wave id (1024 waves)
  const int l   = t & 63;
  const int sub = l >> 4, q = l & 15;
  const float4 a3q = *reinterpret_cast<const float4*>(&a[2 * OUT_DIM + q * 4]);
  for (int r0 = gw * 4; r0 < rows; r0 += 4096) {
    const int r = r0 + sub;
    float v = 0.f;
    if (r < rows) {
      const float4 e4 = *reinterpret_cast<const float4*>(&emb[r * EDGE_DIM + q * 4]);
      v = e4.x * a3q.x + e4.y * a3q.y + e4.z * a3q.z + e4.w * a3q.w;
    }
    v = sum16(v);
    if (q == 0 && r < rows) s3[r] = v;
  }
}

// ========== K2: attention + aggregate + ELU + Y epilogue ==========
// one block (256 thr, 4 waves) per node
__global__ void __launch_bounds__(256) k2_attn_y_kernel(const float* __restrict__ x,
                                                        const float* __restrict__ s1,
                                                        const float* __restrict__ s2,
                                                        const float* __restrict__ s3,
                                                        const int* __restrict__ neigh,
                                                        const int* __restrict__ eidx,
                                                        const float* __restrict__ W2,
                                                        float* __restrict__ out,
                                                        float* __restrict__ Y) {
  const int v = blockIdx.x;
  const int t = threadIdx.x;              // 0..255
  const int w = t >> 6, l = t & 63;
  __shared__ float attC[N_SAMPLE];
  __shared__ int   usC[N_SAMPLE];
  __shared__ float redC[4];
  __shared__ float4 hpC[8][32];
  __shared__ float orow[OUT_DIM];
  __shared__ float partY[4][EDGE_DIM];

  // ---- logits (waves 0,1) ----
  if (t < N_SAMPLE) {
    const int u = neigh[v * N_SAMPLE + t];
    usC[t] = u;
    float e = s1[v] + s2[u] + s3[eidx[v * N_NODES + u]];
    e = e > 0.f ? e : 0.2f * e;           // leaky_relu alpha=0.2
    attC[t] = e;
    const float m = wmax64(e);
    if (l == 0) redC[w] = m;
  }
  __syncthreads();
  const float m = fmaxf(redC[0], redC[1]);
  if (t < N_SAMPLE) {
    const float p = __expf(attC[t] - m);
    attC[t] = p;
    const float s = wsum64(p);
    if (l == 0) redC[2 + w] = s;
  }
  __syncthreads();
  const float inv = 1.0f / (redC[2] + redC[3]);

  // ---- aggregation: wave w owns samples w*32..+31, 2 samples in flight ----
  {
    const int half = l >> 5, cq = l & 31;
    float4 h4 = make_float4(0.f, 0.f, 0.f, 0.f);
    const int s0 = w * 32;
#pragma unroll
    for (int it = 0; it < 16; ++it) {
      const int s = s0 + 2 * it + half;
      const float av = attC[s];
      const float4 xv = *reinterpret_cast<const float4*>(&x[usC[s] * OUT_DIM + cq * 4]);
      h4.x += av * xv.x; h4.y += av * xv.y; h4.z += av * xv.z; h4.w += av * xv.w;
    }
    hpC[w * 2 + half][cq] = h4;
  }
  __syncthreads();
  if (t < 32) {
    float4 H = make_float4(0.f, 0.f, 0.f, 0.f);
#pragma unroll
    for (int p = 0; p < 8; ++p) {
      const float4 v4 = hpC[p][t];
      H.x += v4.x; H.y += v4.y; H.z += v4.z; H.w += v4.w;
    }
    const float4 xs = *reinterpret_cast<const float4*>(&x[v * OUT_DIM + t * 4]);
    float o0 = H.x * inv + xs.x, o1 = H.y * inv + xs.y;
    float o2 = H.z * inv + xs.z, o3 = H.w * inv + xs.w;
    o0 = o0 > 0.f ? o0 : expm1f(o0);      // ELU
    o1 = o1 > 0.f ? o1 : expm1f(o1);
    o2 = o2 > 0.f ? o2 : expm1f(o2);
    o3 = o3 > 0.f ? o3 : expm1f(o3);
    const float4 r = make_float4(o0, o1, o2, o3);
    *reinterpret_cast<float4*>(&out[v * OUT_DIM + t * 4]) = r;
    *reinterpret_cast<float4*>(&orow[t * 4]) = r;
  }
  __syncthreads();

  // ---- Y[v] = orow @ W2  (K split across 4 waves) ----
  {
    const int c = t & 63, ks = t >> 6;
    float acc = 0.f;
#pragma unroll 8
    for (int k = ks * 32; k < ks * 32 + 32; ++k)
      acc += orow[k] * W2[k * EDGE_DIM + c];
    partY[ks][c] = acc;
  }
  __syncthreads();
  if (t < EDGE_DIM)
    Y[v * EDGE_DIM + t] = partY[0][t] + partY[1][t] + partY[2][t] + partY[3][t];
}

// ========== K3: fused edge update ==========
// emb_new[k+1] = relu((emb[eid[k]] @ W3 + Y[i]+Y[j] + B) * emb[k+1])
#define TE 64
__global__ void __launch_bounds__(256) edge_fused_kernel(const float* __restrict__ Y,
                                                         const float* __restrict__ emb,
                                                         const int* __restrict__ eidx,
                                                         const int* __restrict__ tu,
                                                         const float* __restrict__ W3,
                                                         const float* __restrict__ Bv,
                                                         float* __restrict__ emb_new, int n) {
  const int t  = threadIdx.x;
  const int k0 = blockIdx.x * TE;
  __shared__ float Ain[TE][68];
  __shared__ int   tus[2 * TE];

  if (t < 2 * TE) {
    const int idx = 2 * k0 + t;
    tus[t] = (idx < 2 * n) ? tu[idx] : 0;
  }
  {
    const int e  = t >> 2, q = t & 3;
    const int ke = k0 + e;
    if (ke < n) {
      const int i = tu[2 * ke], j = tu[2 * ke + 1];
      const int id = eidx[i * N_NODES + j];
#pragma unroll
      for (int kk = 0; kk < 16; kk += 4) {
        const int k = q * 16 + kk;
        *reinterpret_cast<float4*>(&Ain[e][k]) =
            *reinterpret_cast<const float4*>(&emb[id * EDGE_DIM + k]);
      }
    }
  }
  __syncthreads();

  const int e0 = (t >> 4) * 4;
  const int c0 = (t & 15) * 4;
  const float4 b4 = *reinterpret_cast<const float4*>(&Bv[c0]);
  float4 acc[4];
#pragma unroll
  for (int m = 0; m < 4; ++m) acc[m] = b4;

#pragma unroll 4
  for (int k = 0; k < EDGE_DIM; k += 4) {
    float4 a4[4];
#pragma unroll
    for (int m = 0; m < 4; ++m) a4[m] = *reinterpret_cast<const float4*>(&Ain[e0 + m][k]);
#pragma unroll
    for (int kk = 0; kk < 4; ++kk) {
      const float4 wv = *reinterpret_cast<const float4*>(&W3[(k + kk) * EDGE_DIM + c0]);
#pragma unroll
      for (int m = 0; m < 4; ++m) {
        const float av = reinterpret_cast<const float*>(&a4[m])[kk];
        acc[m].x += av * wv.x; acc[m].y += av * wv.y;
        acc[m].z += av * wv.z; acc[m].w += av * wv.w;
      }
    }
  }

#pragma unroll
  for (int m = 0; m < 4; ++m) {
    const int ke = k0 + e0 + m;
    if (ke < n) {
      const int i = tus[2 * (e0 + m)], j = tus[2 * (e0 + m) + 1];
      const float4 yi = *reinterpret_cast<const float4*>(&Y[i * EDGE_DIM + c0]);
      const float4 yj = *reinterpret_cast<const float4*>(&Y[j * EDGE_DIM + c0]);
      const float4 ek = *reinterpret_cast<const float4*>(&emb[(ke + 1) * EDGE_DIM + c0]);
      float4 r;
      r.x = fmaxf((acc[m].x + yi.x + yj.x) * ek.x, 0.f);
      r.y = fmaxf((acc[m].y + yi.y + yj.y) * ek.y, 0.f);
      r.z = fmaxf((acc[m].z + yi.z + yj.z) * ek.z, 0.f);
      r.w = fmaxf((acc[m].w + yi.w + yj.w) * ek.w, 0.f);
      *reinterpret_cast<float4*>(&emb_new[(ke + 1) * EDGE_DIM + c0]) = r;
    }
  }
  if (blockIdx.x == 0 && t < 16) {
    const int cc = t * 4;
    const float4 b0 = *reinterpret_cast<const float4*>(&Bv[cc]);
    const float4 e0v = *reinterpret_cast<const float4*>(&emb[cc]);
    float4 r;
    r.x = fmaxf(b0.x * e0v.x, 0.f);
    r.y = fmaxf(b0.y * e0v.y, 0.f);
    r.z = fmaxf(b0.z * e0v.z, 0.f);
    r.w = fmaxf(b0.w * e0v.w, 0.f);
    *reinterpret_cast<float4*>(&emb_new[cc]) = r;
  }
}

extern "C" void kernel_launch(void* const* d_in, const int* in_sizes, int n_in,
                              void* d_out, int out_size, void* d_ws, size_t ws_size,
                              hipStream_t stream) {
  const float* feat  = (const float*)d_in[0];
  const int*   eidx  = (const int*)d_in[1];
  const int*   neigh = (const int*)d_in[2];
  const int*   tu    = (const int*)d_in[3];
  const float* emb   = (const float*)d_in[4];
  const float* W     = (const float*)d_in[5];
  const float* W2    = (const float*)d_in[6];
  const float* W3    = (const float*)d_in[7];
  const float* Bv    = (const float*)d_in[8];
  const float* a     = (const float*)d_in[9];
  const int n    = in_sizes[3] / 2;           // edges to update
  const int rows = in_sizes[4] / EDGE_DIM;    // n + 1 emb rows

  float* x  = (float*)d_ws;                   // 4096*128
  float* s1 = x + N_NODES * OUT_DIM;          // 4096
  float* s2 = s1 + N_NODES;                   // 4096
  float* s3 = s2 + N_NODES;                   // rows (padded region 65552)
  float* Y  = s3 + 65552;                     // 4096*64

  float* out_nodes = (float*)d_out;
  float* emb_new   = out_nodes + N_NODES * OUT_DIM;

  hipLaunchKernelGGL(k1_gemm_s_kernel, dim3(N_NODES / 8), dim3(128), 0, stream,
                     feat, W, emb, a, x, s1, s2, s3, rows);
  hipLaunchKernelGGL(k2_attn_y_kernel, dim3(N_NODES), dim3(256), 0, stream,
                     x, s1, s2, s3, neigh, eidx, W2, out_nodes, Y);
  hipLaunchKernelGGL(edge_fused_kernel, dim3((n + TE - 1) / TE), dim3(256), 0, stream,
                     Y, emb, eidx, tu, W3, Bv, emb_new, n);
}

// Round 8
// 175.401 us; speedup vs baseline: 4.9601x; 1.0346x over previous
//
#include <hip/hip_runtime.h>
#include <hip/hip_bf16.h>

#define N_NODES 4096
#define IN_DIM  256
#define OUT_DIM 128
#define EDGE_DIM 64
#define N_SAMPLE 128

__device__ __forceinline__ float wsum64(float v) {
#pragma unroll
  for (int off = 32; off; off >>= 1) v += __shfl_xor(v, off, 64);
  return v;
}
__device__ __forceinline__ float wmax64(float v) {
#pragma unroll
  for (int off = 32; off; off >>= 1) v = fmaxf(v, __shfl_xor(v, off, 64));
  return v;
}
__device__ __forceinline__ float sum16(float v) {   // reduce within 16-lane groups
#pragma unroll
  for (int off = 1; off < 16; off <<= 1) v += __shfl_xor(v, off, 64);
  return v;
}

// ========== K1: x = feat@W (4 rows/block) + xh(bf16) + s1,s2 + s3 + eid_vs ==========
__global__ void __launch_bounds__(128) k1_kernel(const float* __restrict__ feat,
                                                 const float* __restrict__ W,
                                                 const float* __restrict__ emb,
                                                 const int* __restrict__ eidx,
                                                 const int* __restrict__ neigh,
                                                 const float* __restrict__ a,
                                                 float* __restrict__ x,
                                                 ushort* __restrict__ xh,
                                                 float* __restrict__ s1,
                                                 float* __restrict__ s2,
                                                 float* __restrict__ s3,
                                                 int* __restrict__ eid_vs, int rows) {
  const int t  = threadIdx.x;            // 0..127, owns output col t
  const int v0 = blockIdx.x * 4;         // 1024 blocks
  __shared__ float f[4][IN_DIM];
  __shared__ float redA[8], redB[8];

  // early: neighbor ids for this block's 4 rows (coalesced)
  int uq[4];
#pragma unroll
  for (int q = 0; q < 4; ++q) uq[q] = neigh[(v0 + q) * N_SAMPLE + t];

  // stage feat rows
  {
    float4* f4 = reinterpret_cast<float4*>(&f[0][0]);
    const float4* g4 = reinterpret_cast<const float4*>(&feat[v0 * IN_DIM]);
    f4[t]       = g4[t];
    f4[t + 128] = g4[t + 128];
  }
  __syncthreads();

  // issue eid gathers now; values consumed AFTER the FMA loop (latency hidden)
  int eq[4];
#pragma unroll
  for (int q = 0; q < 4; ++q) eq[q] = eidx[(v0 + q) * N_NODES + uq[q]];

  float acc[4] = {0.f, 0.f, 0.f, 0.f};
#pragma unroll 2
  for (int i = 0; i < IN_DIM; i += 4) {
    const float w0 = W[(i + 0) * OUT_DIM + t];
    const float w1 = W[(i + 1) * OUT_DIM + t];
    const float w2 = W[(i + 2) * OUT_DIM + t];
    const float w3 = W[(i + 3) * OUT_DIM + t];
#pragma unroll
    for (int r = 0; r < 4; ++r) {
      const float4 fv = *reinterpret_cast<const float4*>(&f[r][i]);
      acc[r] += fv.x * w0 + fv.y * w1 + fv.z * w2 + fv.w * w3;
    }
  }

  // store eid_vs (gather latency fully hidden behind GEMM)
#pragma unroll
  for (int q = 0; q < 4; ++q) eid_vs[(v0 + q) * N_SAMPLE + t] = eq[q];

  // x (fp32), xh (bf16 RTNE), s1/s2 row dots
  const int wv = t >> 6;
  const float a1t = a[t], a2t = a[OUT_DIM + t];
#pragma unroll
  for (int r = 0; r < 4; ++r) {
    x[(v0 + r) * OUT_DIM + t] = acc[r];
    unsigned int ub = __float_as_uint(acc[r]);
    ub += 0x7FFFu + ((ub >> 16) & 1u);
    xh[(v0 + r) * OUT_DIM + t] = (ushort)(ub >> 16);
    const float q1 = wsum64(acc[r] * a1t);
    const float q2 = wsum64(acc[r] * a2t);
    if ((t & 63) == 0) { redA[wv * 4 + r] = q1; redB[wv * 4 + r] = q2; }
  }
  __syncthreads();
  if (t < 4) {
    s1[v0 + t] = redA[t] + redA[4 + t];
    s2[v0 + t] = redB[t] + redB[4 + t];
  }

  // s3: grid-strided, 4 emb rows per wave-iteration (2048 waves)
  const int gw  = blockIdx.x * 2 + wv;
  const int l   = t & 63;
  const int sub = l >> 4, q16 = l & 15;
  const float4 a3q = *reinterpret_cast<const float4*>(&a[2 * OUT_DIM + q16 * 4]);
  for (int r0 = gw * 4; r0 < rows; r0 += 8192) {
    const int r = r0 + sub;
    float v = 0.f;
    if (r < rows) {
      const float4 e4 = *reinterpret_cast<const float4*>(&emb[r * EDGE_DIM + q16 * 4]);
      v = e4.x * a3q.x + e4.y * a3q.y + e4.z * a3q.z + e4.w * a3q.w;
    }
    v = sum16(v);
    if (q16 == 0 && r < rows) s3[r] = v;
  }
}

// ========== K2: attention + aggregate(bf16) + ELU + Y epilogue ==========
// one block (256 thr, 4 waves) per node
__global__ void __launch_bounds__(256, 4) k2_attn_y_kernel(const float* __restrict__ x,
                                                           const ushort* __restrict__ xh,
                                                           const float* __restrict__ s1,
                                                           const float* __restrict__ s2,
                                                           const float* __restrict__ s3,
                                                           const int* __restrict__ neigh,
                                                           const int* __restrict__ eid_vs,
                                                           const float* __restrict__ W2,
                                                           float* __restrict__ out,
                                                           float* __restrict__ Y) {
  const int v = blockIdx.x;
  const int t = threadIdx.x;              // 0..255
  const int w = t >> 6, l = t & 63;
  __shared__ float attC[N_SAMPLE];
  __shared__ int   usC[N_SAMPLE];
  __shared__ float redC[4];
  __shared__ float4 hpC[8][32];
  __shared__ float orow[OUT_DIM];
  __shared__ float partY[4][EDGE_DIM];

  // ---- logits (waves 0,1): coalesced eid_vs read; s2/s3 gathers L2-hot ----
  if (t < N_SAMPLE) {
    const int u = neigh[v * N_SAMPLE + t];
    const int eid = eid_vs[v * N_SAMPLE + t];
    usC[t] = u;
    float e = s1[v] + s2[u] + s3[eid];
    e = e > 0.f ? e : 0.2f * e;           // leaky_relu alpha=0.2
    attC[t] = e;
    const float m = wmax64(e);
    if (l == 0) redC[w] = m;
  }
  __syncthreads();
  const float m = fmaxf(redC[0], redC[1]);
  if (t < N_SAMPLE) {
    const float p = __expf(attC[t] - m);
    attC[t] = p;
    const float s = wsum64(p);
    if (l == 0) redC[2 + w] = s;
  }
  __syncthreads();
  const float inv = 1.0f / (redC[2] + redC[3]);

  // ---- aggregation: wave w owns samples w*32..+31, bf16 rows (256 B each) ----
  {
    const int half = l >> 5, cq = l & 31;
    float4 h4 = make_float4(0.f, 0.f, 0.f, 0.f);
    const int s0 = w * 32;
#pragma unroll
    for (int it = 0; it < 16; ++it) {
      const int s = s0 + 2 * it + half;
      const float av = attC[s];
      const ushort4 xv = *reinterpret_cast<const ushort4*>(&xh[usC[s] * OUT_DIM + cq * 4]);
      h4.x += av * __uint_as_float((unsigned int)xv.x << 16);
      h4.y += av * __uint_as_float((unsigned int)xv.y << 16);
      h4.z += av * __uint_as_float((unsigned int)xv.z << 16);
      h4.w += av * __uint_as_float((unsigned int)xv.w << 16);
    }
    hpC[w * 2 + half][cq] = h4;
  }
  __syncthreads();
  if (t < 32) {
    float4 H = make_float4(0.f, 0.f, 0.f, 0.f);
#pragma unroll
    for (int p = 0; p < 8; ++p) {
      const float4 v4 = hpC[p][t];
      H.x += v4.x; H.y += v4.y; H.z += v4.z; H.w += v4.w;
    }
    const float4 xs = *reinterpret_cast<const float4*>(&x[v * OUT_DIM + t * 4]);
    float o0 = H.x * inv + xs.x, o1 = H.y * inv + xs.y;
    float o2 = H.z * inv + xs.z, o3 = H.w * inv + xs.w;
    o0 = o0 > 0.f ? o0 : expm1f(o0);      // ELU
    o1 = o1 > 0.f ? o1 : expm1f(o1);
    o2 = o2 > 0.f ? o2 : expm1f(o2);
    o3 = o3 > 0.f ? o3 : expm1f(o3);
    const float4 r = make_float4(o0, o1, o2, o3);
    *reinterpret_cast<float4*>(&out[v * OUT_DIM + t * 4]) = r;
    *reinterpret_cast<float4*>(&orow[t * 4]) = r;
  }
  __syncthreads();

  // ---- Y[v] = orow @ W2  (K split across 4 waves) ----
  {
    const int c = t & 63, ks = t >> 6;
    float acc = 0.f;
#pragma unroll 8
    for (int k = ks * 32; k < ks * 32 + 32; ++k)
      acc += orow[k] * W2[k * EDGE_DIM + c];
    partY[ks][c] = acc;
  }
  __syncthreads();
  if (t < EDGE_DIM)
    Y[v * EDGE_DIM + t] = partY[0][t] + partY[1][t] + partY[2][t] + partY[3][t];
}

// ========== K3: fused edge update ==========
// emb_new[k+1] = relu((emb[eid[k]] @ W3 + Y[i]+Y[j] + B) * emb[k+1])
#define TE 64
__global__ void __launch_bounds__(256) edge_fused_kernel(const float* __restrict__ Y,
                                                         const float* __restrict__ emb,
                                                         const int* __restrict__ eidx,
                                                         const int* __restrict__ tu,
                                                         const float* __restrict__ W3,
                                                         const float* __restrict__ Bv,
                                                         float* __restrict__ emb_new, int n) {
  const int t  = threadIdx.x;
  const int k0 = blockIdx.x * TE;
  __shared__ float Ain[TE][68];
  __shared__ int   tus[2 * TE];

  if (t < 2 * TE) {
    const int idx = 2 * k0 + t;
    tus[t] = (idx < 2 * n) ? tu[idx] : 0;
  }
  {
    const int e  = t >> 2, q = t & 3;
    const int ke = k0 + e;
    if (ke < n) {
      const int i = tu[2 * ke], j = tu[2 * ke + 1];
      const int id = eidx[i * N_NODES + j];
#pragma unroll
      for (int kk = 0; kk < 16; kk += 4) {
        const int k = q * 16 + kk;
        *reinterpret_cast<float4*>(&Ain[e][k]) =
            *reinterpret_cast<const float4*>(&emb[id * EDGE_DIM + k]);
      }
    }
  }
  __syncthreads();

  const int e0 = (t >> 4) * 4;
  const int c0 = (t & 15) * 4;
  const float4 b4 = *reinterpret_cast<const float4*>(&Bv[c0]);
  float4 acc[4];
#pragma unroll
  for (int m = 0; m < 4; ++m) acc[m] = b4;

#pragma unroll 4
  for (int k = 0; k < EDGE_DIM; k += 4) {
    float4 a4[4];
#pragma unroll
    for (int m = 0; m < 4; ++m) a4[m] = *reinterpret_cast<const float4*>(&Ain[e0 + m][k]);
#pragma unroll
    for (int kk = 0; kk < 4; ++kk) {
      const float4 wv = *reinterpret_cast<const float4*>(&W3[(k + kk) * EDGE_DIM + c0]);
#pragma unroll
      for (int m = 0; m < 4; ++m) {
        const float av = reinterpret_cast<const float*>(&a4[m])[kk];
        acc[m].x += av * wv.x; acc[m].y += av * wv.y;
        acc[m].z += av * wv.z; acc[m].w += av * wv.w;
      }
    }
  }

#pragma unroll
  for (int m = 0; m < 4; ++m) {
    const int ke = k0 + e0 + m;
    if (ke < n) {
      const int i = tus[2 * (e0 + m)], j = tus[2 * (e0 + m) + 1];
      const float4 yi = *reinterpret_cast<const float4*>(&Y[i * EDGE_DIM + c0]);
      const float4 yj = *reinterpret_cast<const float4*>(&Y[j * EDGE_DIM + c0]);
      const float4 ek = *reinterpret_cast<const float4*>(&emb[(ke + 1) * EDGE_DIM + c0]);
      float4 r;
      r.x = fmaxf((acc[m].x + yi.x + yj.x) * ek.x, 0.f);
      r.y = fmaxf((acc[m].y + yi.y + yj.y) * ek.y, 0.f);
      r.z = fmaxf((acc[m].z + yi.z + yj.z) * ek.z, 0.f);
      r.w = fmaxf((acc[m].w + yi.w + yj.w) * ek.w, 0.f);
      *reinterpret_cast<float4*>(&emb_new[(ke + 1) * EDGE_DIM + c0]) = r;
    }
  }
  if (blockIdx.x == 0 && t < 16) {
    const int cc = t * 4;
    const float4 b0 = *reinterpret_cast<const float4*>(&Bv[cc]);
    const float4 e0v = *reinterpret_cast<const float4*>(&emb[cc]);
    float4 r;
    r.x = fmaxf(b0.x * e0v.x, 0.f);
    r.y = fmaxf(b0.y * e0v.y, 0.f);
    r.z = fmaxf(b0.z * e0v.z, 0.f);
    r.w = fmaxf(b0.w * e0v.w, 0.f);
    *reinterpret_cast<float4*>(&emb_new[cc]) = r;
  }
}

extern "C" void kernel_launch(void* const* d_in, const int* in_sizes, int n_in,
                              void* d_out, int out_size, void* d_ws, size_t ws_size,
                              hipStream_t stream) {
  const float* feat  = (const float*)d_in[0];
  const int*   eidx  = (const int*)d_in[1];
  const int*   neigh = (const int*)d_in[2];
  const int*   tu    = (const int*)d_in[3];
  const float* emb   = (const float*)d_in[4];
  const float* W     = (const float*)d_in[5];
  const float* W2    = (const float*)d_in[6];
  const float* W3    = (const float*)d_in[7];
  const float* Bv    = (const float*)d_in[8];
  const float* a     = (const float*)d_in[9];
  const int n    = in_sizes[3] / 2;           // edges to update
  const int rows = in_sizes[4] / EDGE_DIM;    // n + 1 emb rows

  float* ws = (float*)d_ws;
  float* x      = ws;                         // 524288 f32
  float* s1     = ws + 524288;                // 4096
  float* s2     = ws + 528384;                // 4096
  float* s3     = ws + 532480;                // 65552 (rows <= 65537)
  float* Y      = ws + 598032;                // 262144
  ushort* xh    = (ushort*)(ws + 860176);     // 524288 bf16 (262144 f32 slots)
  int*  eid_vs  = (int*)(ws + 1122320);       // 524288 int

  float* out_nodes = (float*)d_out;
  float* emb_new   = out_nodes + N_NODES * OUT_DIM;

  hipLaunchKernelGGL(k1_kernel, dim3(N_NODES / 4), dim3(128), 0, stream,
                     feat, W, emb, eidx, neigh, a, x, xh, s1, s2, s3, eid_vs, rows);
  hipLaunchKernelGGL(k2_attn_y_kernel, dim3(N_NODES), dim3(256), 0, stream,
                     x, xh, s1, s2, s3, neigh, eid_vs, W2, out_nodes, Y);
  hipLaunchKernelGGL(edge_fused_kernel, dim3((n + TE - 1) / TE), dim3(256), 0, stream,
                     Y, emb, eidx, tu, W3, Bv, emb_new, n);
}